// Round 16
// baseline (279.425 us; speedup 1.0000x reference)
//
#include <hip/hip_runtime.h>
#include <math.h>

#define S_DIM 8
#define SA_DIM 10
#define NN 256

// ---------------- workspace layout (float offsets) ----------------
constexpr size_t OFF_K     = 0;                          // 8*256*256  (K, then LT in-place)
constexpr size_t OFF_LINV  = OFF_K    + 8ull*NN*NN;      // 8*256*256
constexpr size_t OFF_KINV  = OFF_LINV + 8ull*NN*NN;      // 8*256*256
constexpr size_t OFF_RD    = OFF_KINV + 8ull*NN*NN;      // 8*256 reciprocal diag of L
constexpr size_t OFF_U     = OFF_RD   + 8*NN;            // 8*256*10
constexpr size_t OFF_LK    = OFF_U    + 8*NN*SA_DIM;     // 8*256
constexpr size_t OFF_M     = OFF_LK   + 8*NN;            // 64*100    M_ab
constexpr size_t OFF_C     = OFF_M    + 64*100;          // 64        -0.5*logdet R
constexpr size_t OFF_AINV  = OFF_C    + 64;              // 8*100
constexpr size_t OFF_AIM   = OFF_AINV + 800;             // 8*10
constexpr size_t OFF_MDC   = OFF_AIM  + 80;              // 8
constexpr size_t OFF_BETA  = OFF_MDC  + 8;               // 8*256
constexpr size_t OFF_MEAN  = OFF_BETA + 8*NN;            // 8
constexpr size_t OFF_CROSS = OFF_MEAN + 8;               // 80
constexpr size_t OFF_COVP  = OFF_CROSS+ 80;              // 512 partials (eighths)
constexpr size_t OFF_TRP   = OFF_COVP + 512;             // 64

// ---------------- Gauss-Jordan inverse, 10x10, no pivoting ----------------
__device__ void gj_invert10(float A[SA_DIM][SA_DIM], float B[SA_DIM][SA_DIM], float* logdet) {
#pragma unroll
  for (int i = 0; i < SA_DIM; i++)
#pragma unroll
    for (int j = 0; j < SA_DIM; j++) B[i][j] = (i == j) ? 1.f : 0.f;
  float ld = 0.f;
#pragma unroll
  for (int k = 0; k < SA_DIM; k++) {
    float pv = A[k][k];
    ld += logf(pv);
    float ip = 1.f / pv;
#pragma unroll
    for (int j = 0; j < SA_DIM; j++) { A[k][j] *= ip; B[k][j] *= ip; }
#pragma unroll
    for (int r = 0; r < SA_DIM; r++) {
      if (r == k) continue;
      float f = A[r][k];
#pragma unroll
      for (int j = 0; j < SA_DIM; j++) { A[r][j] -= f * A[k][j]; B[r][j] -= f * B[k][j]; }
    }
  }
  *logdet = ld;
}

// ---------------- K-front9: prep u/lk (blocks 0..7) | small 10x10 LA (block 8) --------
__global__ __launch_bounds__(256) void k_front9(const float* __restrict__ x,
                                                const float* __restrict__ mf,
                                                const float* __restrict__ cov,
                                                const float* __restrict__ eqc,
                                                const float* __restrict__ scales,
                                                float* __restrict__ u,
                                                float* __restrict__ lkw,
                                                float* __restrict__ Mw, float* __restrict__ cvec,
                                                float* __restrict__ Ainvw, float* __restrict__ aimw,
                                                float* __restrict__ mdcw) {
  int blk = blockIdx.x;
  if (blk < 8) {
    int g = blk;
    int n = threadIdx.x;
    float quad = 0.f;
#pragma unroll
    for (int d = 0; d < SA_DIM; d++) {
      float isc = 1.0f / scales[g * SA_DIM + d];
      float nu = x[n * SA_DIM + d] - mf[d];
      u[((size_t)g * NN + n) * SA_DIM + d] = nu * isc;
      quad += nu * nu * isc;
    }
    lkw[g * NN + n] = logf(eqc[g]) - 0.5f * quad;
  } else {
    int p = threadIdx.x;
    if (p >= 64) return;
    int a = p >> 3, b = p & 7;
    float A[SA_DIM][SA_DIM], B[SA_DIM][SA_DIM];
    for (int i = 0; i < SA_DIM; i++)
      for (int j = 0; j < SA_DIM; j++)
        A[i][j] = cov[i * SA_DIM + j] * (1.f / scales[a * SA_DIM + j] + 1.f / scales[b * SA_DIM + j]) +
                  ((i == j) ? 1.f : 0.f);
    float ld;
    gj_invert10(A, B, &ld);
    cvec[p] = -0.5f * ld;
    for (int i = 0; i < SA_DIM; i++)
      for (int j = 0; j < SA_DIM; j++) {
        float v = 0.f;
        for (int k = 0; k < SA_DIM; k++) v += B[i][k] * cov[k * SA_DIM + j];
        Mw[p * 100 + i * SA_DIM + j] = v;
      }
    if (b == 0) {
      int g = a;
      for (int i = 0; i < SA_DIM; i++)
        for (int j = 0; j < SA_DIM; j++)
          A[i][j] = cov[i * SA_DIM + j] + ((i == j) ? scales[g * SA_DIM + j] : 0.f);
      float ld2;
      gj_invert10(A, B, &ld2);
      for (int i = 0; i < SA_DIM; i++)
        for (int j = 0; j < SA_DIM; j++) Ainvw[g * 100 + i * SA_DIM + j] = B[i][j];
      for (int i = 0; i < SA_DIM; i++) {
        float v = 0.f;
        for (int j = 0; j < SA_DIM; j++) v += B[i][j] * mf[j];
        aimw[g * SA_DIM + i] = v;
      }
      for (int i = 0; i < SA_DIM; i++)
        for (int j = 0; j < SA_DIM; j++)
          A[i][j] = cov[i * SA_DIM + j] * (1.f / scales[g * SA_DIM + j]) + ((i == j) ? 1.f : 0.f);
      float ld3;
      gj_invert10(A, B, &ld3);
      mdcw[g] = eqc[g] * __expf(-0.5f * ld3);
    }
  }
}

__device__ __forceinline__ void tile_idx(int tau, int ntile, int nt4, int c0,
                                         int& ib, int& jb, int& iq, int& jq) {
  int rt = ntile - 1 - tau;
  int q = (int)((sqrtf((float)(8 * rt + 1)) - 1.0f) * 0.5f);
  while ((q + 1) * (q + 2) / 2 <= rt) q++;
  while (q * (q + 1) / 2 > rt) q--;
  jq = nt4 - 1 - q;
  int rem = rt - q * (q + 1) / 2;
  iq = nt4 - 1 - rem;
  jb = c0 + 16 + 4 * jq;
  ib = c0 + 16 + 4 * iq;
}

// ---- factor one 16-col panel (proven chol8 body) ----
__device__ __forceinline__ void chol_factor_panel(float* __restrict__ Ag,
                                                  float* __restrict__ rdg,
                                                  int c0, int nb, int t, int lane,
                                                  bool fromGlobal,
                                                  const float (*SRC)[248],
                                                  float (*Pdst)[248]) {
  int rr = lane & 15;
  float a[16];
  float myrs = 0.f;
  if (fromGlobal) {
#pragma unroll
    for (int j = 0; j < 16; j++)
      a[j] = (j <= rr) ? Ag[(size_t)(c0 + j) * NN + (c0 + rr)]
                       : Ag[(size_t)(c0 + rr) * NN + (c0 + j)];
  } else {
#pragma unroll
    for (int j = 0; j < 16; j++)
      a[j] = (j <= rr) ? SRC[j][rr] : SRC[rr][j];
  }
#pragma unroll
  for (int k = 0; k < 16; k++) {
    float d = __shfl(a[k], k);
    float rs_ = rsqrtf(d);
    if (rr == k) myrs = rs_;
    float m = a[k] * rs_;
#pragma unroll
    for (int j = 0; j < 16; j++) {
      if (j > k) {
        float Lkj = __shfl(a[j], k) * rs_;
        a[j] = fmaf(-m, Lkj, a[j]);
      }
    }
    a[k] = m;
  }
  if (t < 16) {
    rdg[c0 + rr] = myrs;
#pragma unroll
    for (int j = 0; j < 16; j++)
      if (j <= rr) Ag[(size_t)(c0 + j) * NN + (c0 + rr)] = a[j];
  }
  if (t < nb) {
    int i = c0 + 16 + t;
    float xs[16];
#pragma unroll
    for (int c = 0; c < 16; c++) {
      float x = fromGlobal ? Ag[(size_t)(c0 + c) * NN + i] : SRC[c][16 + t];
#pragma unroll
      for (int cp = 0; cp < 16; cp++) {
        if (cp < c) {
          float Lccp = __shfl(a[cp], c);
          x = fmaf(-Lccp, xs[cp], x);
        }
      }
      xs[c] = x * __shfl(myrs, c);
    }
#pragma unroll
    for (int c = 0; c < 16; c++) {
      Ag[(size_t)(c0 + c) * NN + i] = xs[c];
      Pdst[c][t] = xs[c];
    }
  }
}

// ---------------- K1: K-build prologue + lookahead Cholesky (chol8 body, best=104us) ----
// Prologue: block g builds its own K[g] (x staged in NP before NP's first real use;
// 64 coalesced elems/thread + exp; same-block global write->read ordered by the
// __syncthreads vmcnt drain). Then chol8: per panel p, C(p)->NP; barrier;
// { F(p+1) waves 0-3 } || { B(p) single-tile bulk, waves 4-15 }; barrier.
__global__ __launch_bounds__(1024, 4) void k_cholK(const float* __restrict__ x,
                                                   const float* __restrict__ eqc,
                                                   const float* __restrict__ scales,
                                                   const float* __restrict__ noise,
                                                   float* __restrict__ Aw,
                                                   float* __restrict__ rd) {
  int g = blockIdx.x;
  float* Ag = Aw + (size_t)g * NN * NN;
  float* rdg = rd + g * NN;
  int t = threadIdx.x;
  int lane = t & 63;
  int w = t >> 6;
  __shared__ __align__(16) float P[2][16][248];
  __shared__ __align__(16) float NP[16][248];
  __shared__ float iscs[16];

  // ---- prologue: build K[g] ----
  {
    float* xs = &NP[0][0];   // 2560 floats needed; NP has 3968
    for (int i = t; i < NN * SA_DIM; i += 1024) xs[i] = x[i];
    if (t < SA_DIM) iscs[t] = 1.0f / scales[g * SA_DIM + t];
    __syncthreads();
    float eq = eqc[g], nz = noise[g];
    for (int e = t; e < NN * NN; e += 1024) {
      int n = e >> 8, m = e & 255;
      float quad = 0.f;
#pragma unroll
      for (int d = 0; d < SA_DIM; d++) {
        float df = xs[n * SA_DIM + d] - xs[m * SA_DIM + d];
        quad += df * df * iscs[d];
      }
      float v = eq * __expf(-0.5f * quad);
      if (n == m) v += nz;
      Ag[e] = v;
    }
    __syncthreads();   // drains vmcnt -> K visible to same-block reads
  }

  if (w < 4)
    chol_factor_panel(Ag, rdg, 0, 240, t, lane, true, nullptr, P[0]);
  __syncthreads();

  for (int p = 0; p < 15; p++) {
    int c0 = 16 * p;
    int nb = NN - c0 - 16;   // >= 16
    int nt4 = nb >> 2;       // >= 4
    const float (*Pc)[248] = P[p & 1];
    // ---------------- C(p): critical tiles (jq < 4) -> NP, LDS only ----------------
    int ncrit = 4 * nt4 - 6;
    if (t < ncrit) {
      int jq, iq;
      if (t < nt4) { jq = 0; iq = t; }
      else if (t < 2 * nt4 - 1) { jq = 1; iq = t - nt4 + 1; }
      else if (t < 3 * nt4 - 3) { jq = 2; iq = t - (2 * nt4 - 1) + 2; }
      else { jq = 3; iq = t - (3 * nt4 - 3) + 3; }
      int jb = c0 + 16 + 4 * jq, ib = c0 + 16 + 4 * iq;
      float4 cv0 = *(const float4*)(Ag + (size_t)(jb + 0) * NN + ib);
      float4 cv1 = *(const float4*)(Ag + (size_t)(jb + 1) * NN + ib);
      float4 cv2 = *(const float4*)(Ag + (size_t)(jb + 2) * NN + ib);
      float4 cv3 = *(const float4*)(Ag + (size_t)(jb + 3) * NN + ib);
      float4 a0 = make_float4(0.f, 0.f, 0.f, 0.f), a1 = a0, a2 = a0, a3 = a0;
#pragma unroll
      for (int k = 0; k < 16; k++) {
        float4 pi = *(const float4*)(&Pc[k][4 * iq]);
        float4 pj = *(const float4*)(&Pc[k][4 * jq]);
        a0.x = fmaf(pj.x, pi.x, a0.x); a0.y = fmaf(pj.x, pi.y, a0.y);
        a0.z = fmaf(pj.x, pi.z, a0.z); a0.w = fmaf(pj.x, pi.w, a0.w);
        a1.x = fmaf(pj.y, pi.x, a1.x); a1.y = fmaf(pj.y, pi.y, a1.y);
        a1.z = fmaf(pj.y, pi.z, a1.z); a1.w = fmaf(pj.y, pi.w, a1.w);
        a2.x = fmaf(pj.z, pi.x, a2.x); a2.y = fmaf(pj.z, pi.y, a2.y);
        a2.z = fmaf(pj.z, pi.z, a2.z); a2.w = fmaf(pj.z, pi.w, a2.w);
        a3.x = fmaf(pj.w, pi.x, a3.x); a3.y = fmaf(pj.w, pi.y, a3.y);
        a3.z = fmaf(pj.w, pi.z, a3.z); a3.w = fmaf(pj.w, pi.w, a3.w);
      }
      cv0.x -= a0.x; cv0.y -= a0.y; cv0.z -= a0.z; cv0.w -= a0.w;
      cv1.x -= a1.x; cv1.y -= a1.y; cv1.z -= a1.z; cv1.w -= a1.w;
      cv2.x -= a2.x; cv2.y -= a2.y; cv2.z -= a2.z; cv2.w -= a2.w;
      cv3.x -= a3.x; cv3.y -= a3.y; cv3.z -= a3.z; cv3.w -= a3.w;
      *(float4*)(&NP[4 * jq + 0][4 * iq]) = cv0;
      *(float4*)(&NP[4 * jq + 1][4 * iq]) = cv1;
      *(float4*)(&NP[4 * jq + 2][4 * iq]) = cv2;
      *(float4*)(&NP[4 * jq + 3][4 * iq]) = cv3;
    }
    __syncthreads();
    if (w < 4) {
      chol_factor_panel(Ag, rdg, c0 + 16, nb - 16, t, lane, false, NP, P[(p + 1) & 1]);
    } else {
      int nt4b = nt4 - 4;
      int ntileB = nt4b * (nt4b + 1) / 2;
      for (int tau = t - 256; tau < ntileB; tau += 768) {
        int ib, jb, iq, jq;
        tile_idx(tau, ntileB, nt4b, c0 + 16, ib, jb, iq, jq);
        float4 cv0 = *(const float4*)(Ag + (size_t)(jb + 0) * NN + ib);
        float4 cv1 = *(const float4*)(Ag + (size_t)(jb + 1) * NN + ib);
        float4 cv2 = *(const float4*)(Ag + (size_t)(jb + 2) * NN + ib);
        float4 cv3 = *(const float4*)(Ag + (size_t)(jb + 3) * NN + ib);
        float4 a0 = make_float4(0.f, 0.f, 0.f, 0.f), a1 = a0, a2 = a0, a3 = a0;
#pragma unroll
        for (int k = 0; k < 16; k++) {
          float4 pi = *(const float4*)(&Pc[k][16 + 4 * iq]);
          float4 pj = *(const float4*)(&Pc[k][16 + 4 * jq]);
          a0.x = fmaf(pj.x, pi.x, a0.x); a0.y = fmaf(pj.x, pi.y, a0.y);
          a0.z = fmaf(pj.x, pi.z, a0.z); a0.w = fmaf(pj.x, pi.w, a0.w);
          a1.x = fmaf(pj.y, pi.x, a1.x); a1.y = fmaf(pj.y, pi.y, a1.y);
          a1.z = fmaf(pj.y, pi.z, a1.z); a1.w = fmaf(pj.y, pi.w, a1.w);
          a2.x = fmaf(pj.z, pi.x, a2.x); a2.y = fmaf(pj.z, pi.y, a2.y);
          a2.z = fmaf(pj.z, pi.z, a2.z); a2.w = fmaf(pj.z, pi.w, a2.w);
          a3.x = fmaf(pj.w, pi.x, a3.x); a3.y = fmaf(pj.w, pi.y, a3.y);
          a3.z = fmaf(pj.w, pi.z, a3.z); a3.w = fmaf(pj.w, pi.w, a3.w);
        }
        cv0.x -= a0.x; cv0.y -= a0.y; cv0.z -= a0.z; cv0.w -= a0.w;
        cv1.x -= a1.x; cv1.y -= a1.y; cv1.z -= a1.z; cv1.w -= a1.w;
        cv2.x -= a2.x; cv2.y -= a2.y; cv2.z -= a2.z; cv2.w -= a2.w;
        cv3.x -= a3.x; cv3.y -= a3.y; cv3.z -= a3.z; cv3.w -= a3.w;
        *(float4*)(Ag + (size_t)(jb + 0) * NN + ib) = cv0;
        *(float4*)(Ag + (size_t)(jb + 1) * NN + ib) = cv1;
        *(float4*)(Ag + (size_t)(jb + 2) * NN + ib) = cv2;
        *(float4*)(Ag + (size_t)(jb + 3) * NN + ib) = cv3;
      }
    }
    __syncthreads();
  }
}

// ---------------- K2: BLOCKED triangular inverse -------------------------------------
__global__ __launch_bounds__(256) void k_linv2(const float* __restrict__ LT,
                                               const float* __restrict__ rd,
                                               float* __restrict__ Linv) {
  int g = blockIdx.x >> 2;
  int q = blockIdx.x & 3;
  int w = threadIdx.x >> 6;
  int lane = threadIdx.x & 63;
  int j = 4 * q + w;
  const float* Ag = LT + (size_t)g * NN * NN;
  const float* rdg = rd + g * NN;
  float* Og = Linv + (size_t)g * NN * NN;
  __shared__ __align__(16) float Xl[4][16][16][16];
  __shared__ __align__(16) float Dv[16][16][16];
  int r = lane & 15, cq = lane >> 4;

  for (int s = 0; s < 4; s++) {
    int i = w + 4 * s;
    for (int e = lane; e < 256; e += 64) {
      int k = e >> 4, rr = e & 15;
      Xl[w][s][k][rr] = Ag[(size_t)(16 * i + k) * NN + 16 * i + rr];
    }
    asm volatile("s_waitcnt lgkmcnt(0)" ::: "memory");
    __builtin_amdgcn_sched_barrier(0);
    int c = lane & 15;
    float xv[16];
#pragma unroll
    for (int rr = 0; rr < 16; rr++) {
      float tmp = (rr == c) ? 1.f : 0.f;
#pragma unroll
      for (int m = 0; m < 16; m++) {
        if (m < rr) tmp = fmaf(-Xl[w][s][m][rr], xv[m], tmp);
      }
      xv[rr] = tmp * rdg[16 * i + rr];
    }
    if (lane < 16) {
#pragma unroll
      for (int rr = 0; rr < 16; rr++) Dv[i][rr][lane] = xv[rr];
    }
  }
  __syncthreads();

  {
    float4 dj = *(const float4*)&Dv[j][r][4 * cq];
    *(float4*)&Xl[w][j][r][4 * cq] = dj;
    *(float4*)(Og + (size_t)(16 * j + r) * NN + 16 * j + 4 * cq) = dj;
    float4 z = make_float4(0.f, 0.f, 0.f, 0.f);
    for (int i2 = 0; i2 < j; i2++)
      *(float4*)(Og + (size_t)(16 * i2 + r) * NN + 16 * j + 4 * cq) = z;
  }
  asm volatile("s_waitcnt lgkmcnt(0)" ::: "memory");
  __builtin_amdgcn_sched_barrier(0);

  for (int i = j + 1; i < 16; i++) {
    float4 acc = make_float4(0.f, 0.f, 0.f, 0.f);
    for (int k = j; k < i; k++) {
      const float* Lbase = Ag + (size_t)(16 * k) * NN + 16 * i + r;
      const float* Xk = &Xl[w][k][0][4 * cq];
#pragma unroll
      for (int m = 0; m < 16; m++) {
        float lv = Lbase[(size_t)m * NN];
        float4 xvv = *(const float4*)(Xk + 16 * m);
        acc.x = fmaf(lv, xvv.x, acc.x);
        acc.y = fmaf(lv, xvv.y, acc.y);
        acc.z = fmaf(lv, xvv.z, acc.z);
        acc.w = fmaf(lv, xvv.w, acc.w);
      }
    }
    float4 o = make_float4(0.f, 0.f, 0.f, 0.f);
#pragma unroll
    for (int m = 0; m < 16; m++) {
      float d = Dv[i][r][m];
      float sx = __shfl(acc.x, m + 16 * cq);
      float sy = __shfl(acc.y, m + 16 * cq);
      float sz = __shfl(acc.z, m + 16 * cq);
      float sw = __shfl(acc.w, m + 16 * cq);
      o.x = fmaf(-d, sx, o.x);
      o.y = fmaf(-d, sy, o.y);
      o.z = fmaf(-d, sz, o.z);
      o.w = fmaf(-d, sw, o.w);
    }
    *(float4*)&Xl[w][i][r][4 * cq] = o;
    *(float4*)(Og + (size_t)(16 * i + r) * NN + 16 * j + 4 * cq) = o;
    asm volatile("s_waitcnt lgkmcnt(0)" ::: "memory");
    __builtin_amdgcn_sched_barrier(0);
  }
}

// ---------------- K3: Kinv = Linv^T Linv, SYMMETRIC (10 upper tiles, mirror via LDS) ----
__global__ __launch_bounds__(256) void k_syrk2(const float* __restrict__ Linv,
                                               float* __restrict__ Kinv) {
  int g = blockIdx.x / 10;
  int tile = blockIdx.x - g * 10;
  int ti = 0, rem = tile;
  while (rem >= 4 - ti) { rem -= 4 - ti; ti++; }
  int tj = ti + rem;
  int i0 = ti * 64, j0 = tj * 64;
  const float* A = Linv + (size_t)g * NN * NN;
  float* O = Kinv + (size_t)g * NN * NN;
  __shared__ __align__(16) float smem[4096];
  float* sa = smem;
  float* sb = smem + 2048;
  int tx = threadIdx.x & 15, ty = threadIdx.x >> 4;
  float acc[4][4] = {{0.f}};
  for (int k0 = 0; k0 < NN; k0 += 32) {
    for (int e = threadIdx.x; e < 2048; e += 256) {
      int kk = e >> 6, cc = e & 63;
      sa[kk * 64 + cc] = A[(size_t)(k0 + kk) * NN + i0 + cc];
      sb[kk * 64 + cc] = A[(size_t)(k0 + kk) * NN + j0 + cc];
    }
    __syncthreads();
#pragma unroll 8
    for (int kk = 0; kk < 32; kk++) {
      float4 av = *(const float4*)(&sa[kk * 64 + ty * 4]);
      float4 bv = *(const float4*)(&sb[kk * 64 + tx * 4]);
      acc[0][0] = fmaf(av.x, bv.x, acc[0][0]); acc[0][1] = fmaf(av.x, bv.y, acc[0][1]);
      acc[0][2] = fmaf(av.x, bv.z, acc[0][2]); acc[0][3] = fmaf(av.x, bv.w, acc[0][3]);
      acc[1][0] = fmaf(av.y, bv.x, acc[1][0]); acc[1][1] = fmaf(av.y, bv.y, acc[1][1]);
      acc[1][2] = fmaf(av.y, bv.z, acc[1][2]); acc[1][3] = fmaf(av.y, bv.w, acc[1][3]);
      acc[2][0] = fmaf(av.z, bv.x, acc[2][0]); acc[2][1] = fmaf(av.z, bv.y, acc[2][1]);
      acc[2][2] = fmaf(av.z, bv.z, acc[2][2]); acc[2][3] = fmaf(av.z, bv.w, acc[2][3]);
      acc[3][0] = fmaf(av.w, bv.x, acc[3][0]); acc[3][1] = fmaf(av.w, bv.y, acc[3][1]);
      acc[3][2] = fmaf(av.w, bv.z, acc[3][2]); acc[3][3] = fmaf(av.w, bv.w, acc[3][3]);
    }
    __syncthreads();
  }
#pragma unroll
  for (int q = 0; q < 4; q++)
#pragma unroll
    for (int r = 0; r < 4; r++)
      O[(size_t)(i0 + ty * 4 + q) * NN + j0 + tx * 4 + r] = acc[q][r];
  if (ti != tj) {
    __syncthreads();
#pragma unroll
    for (int q = 0; q < 4; q++)
#pragma unroll
      for (int r = 0; r < 4; r++)
        smem[(ty * 4 + q) * 64 + tx * 4 + r] = acc[q][r];
    __syncthreads();
    for (int e = threadIdx.x; e < 1024; e += 256) {
      int rr = e >> 4, c4 = (e & 15) * 4;
      float4 v = make_float4(smem[(c4 + 0) * 64 + rr], smem[(c4 + 1) * 64 + rr],
                             smem[(c4 + 2) * 64 + rr], smem[(c4 + 3) * 64 + rr]);
      *(float4*)(O + (size_t)(j0 + rr) * NN + i0 + c4) = v;
    }
  }
}

// ---------------- K4: beta = Kinv @ y (once, 8 blocks) ----------------
__global__ __launch_bounds__(256) void k_beta(const float* __restrict__ Kinv,
                                              const float* __restrict__ y,
                                              float* __restrict__ betaw) {
  int g = blockIdx.x, n = threadIdx.x;
  __shared__ __align__(16) float ys[NN];
  ys[n] = y[n * S_DIM + g];
  __syncthreads();
  const float4* Kg = (const float4*)(Kinv + (size_t)g * NN * NN + (size_t)n * NN);
  float acc = 0.f;
  for (int m4 = 0; m4 < 64; m4++) {
    float4 kv = Kg[m4];
    float4 yv = ((const float4*)ys)[m4];
    acc += kv.x * yv.x + kv.y * yv.y + kv.z * yv.z + kv.w * yv.w;
  }
  betaw[g * NN + n] = acc;
}

// ---------------- K-back: fused Q reduction (blocks 0..511) + mean/cross (512..519) ----
__global__ __launch_bounds__(256) void k_back(const float* __restrict__ u,
                                              const float* __restrict__ lkw,
                                              const float* __restrict__ Mw,
                                              const float* __restrict__ cvec,
                                              const float* __restrict__ Kinv,
                                              const float* __restrict__ betaw,
                                              const float* __restrict__ x,
                                              const float* __restrict__ mf,
                                              const float* __restrict__ cov,
                                              const float* __restrict__ scales,
                                              const float* __restrict__ Ainvw,
                                              const float* __restrict__ aimw,
                                              const float* __restrict__ mdcw,
                                              float* __restrict__ covp, float* __restrict__ trp,
                                              float* __restrict__ meanw, float* __restrict__ crossw) {
  int blk = blockIdx.x;
  int t = threadIdx.x;
  if (blk < 512) {
    int p = blk >> 3;
    int eighth = blk & 7;
    int a = p >> 3, b = p & 7;
    __shared__ __align__(16) float ub[NN * 12];
    __shared__ float Ms[100];
    __shared__ float sbv[NN];
    __shared__ float eb[NN];
    __shared__ float red[256];
    {
      const float* ur = u + (size_t)b * NN * SA_DIM + (size_t)t * SA_DIM;
      float* ud = &ub[t * 12];
#pragma unroll
      for (int d = 0; d < SA_DIM; d++) ud[d] = ur[d];
    }
    if (t < 100) Ms[t] = Mw[p * 100 + t];
    eb[t] = betaw[b * NN + t];
    __syncthreads();
    {
      const float* um = &ub[t * 12];
      float qd = 0.f;
#pragma unroll
      for (int d = 0; d < SA_DIM; d++) {
        float v = 0.f;
#pragma unroll
        for (int e = 0; e < SA_DIM; e++) v += Ms[d * SA_DIM + e] * um[e];
        qd += v * um[d];
      }
      sbv[t] = lkw[b * NN + t] + 0.5f * qd;
    }
    __syncthreads();
    int n = eighth * 32 + (t >> 3);
    int c = t & 7;
    float ua[SA_DIM];
#pragma unroll
    for (int d = 0; d < SA_DIM; d++) ua[d] = u[((size_t)a * NN + n) * SA_DIM + d];
    float va[SA_DIM];
#pragma unroll
    for (int d = 0; d < SA_DIM; d++) {
      float v = 0.f;
#pragma unroll
      for (int e = 0; e < SA_DIM; e++) v += Ms[d * SA_DIM + e] * ua[e];
      va[d] = v;
    }
    float qa = 0.f;
#pragma unroll
    for (int d = 0; d < SA_DIM; d++) qa += va[d] * ua[d];
    float pa = lkw[a * NN + n] + 0.5f * qa + cvec[p];
    float wa = betaw[a * NN + n];
    const float* Krow = Kinv + (size_t)a * NN * NN + (size_t)n * NN;
    float covacc = 0.f, tracc = 0.f;
    bool dg = (a == b);
    for (int ii = 0; ii < 32; ii++) {
      int mm = c + 8 * ii;
      const float* ur = &ub[mm * 12];
      float4 f0 = *(const float4*)ur;
      float4 f1 = *(const float4*)(ur + 4);
      float4 f2 = *(const float4*)(ur + 8);
      float s = pa + sbv[mm];
      s += va[0] * f0.x + va[1] * f0.y + va[2] * f0.z + va[3] * f0.w;
      s += va[4] * f1.x + va[5] * f1.y + va[6] * f1.z + va[7] * f1.w;
      s += va[8] * f2.x + va[9] * f2.y;
      float e = __expf(s);
      covacc += eb[mm] * e;
      if (dg) tracc += Krow[mm] * e;
    }
    covacc *= wa;
    red[t] = covacc;
    __syncthreads();
    for (int st = 128; st > 0; st >>= 1) {
      if (t < st) red[t] += red[t + st];
      __syncthreads();
    }
    if (t == 0) covp[blk] = red[0];
    if (dg) {
      red[t] = tracc;
      __syncthreads();
      for (int st = 128; st > 0; st >>= 1) {
        if (t < st) red[t] += red[t + st];
        __syncthreads();
      }
      if (t == 0) trp[a * 8 + eighth] = red[0];
    }
  } else {
    int g = blk - 512;
    int i = t;
    __shared__ float Ai[100], cv[100], aims[SA_DIM], sc[SA_DIM], mfs[SA_DIM];
    __shared__ float red[256];
    if (i < 100) { Ai[i] = Ainvw[g * 100 + i]; cv[i] = cov[i]; }
    if (i < SA_DIM) { aims[i] = aimw[g * SA_DIM + i]; sc[i] = scales[g * SA_DIM + i]; mfs[i] = mf[i]; }
    __syncthreads();
    float bg = betaw[g * NN + i];
    float xi[SA_DIM], nu[SA_DIM];
#pragma unroll
    for (int d = 0; d < SA_DIM; d++) { xi[d] = x[i * SA_DIM + d]; nu[d] = xi[d] - mfs[d]; }
    float sv[SA_DIM], ad[SA_DIM];
#pragma unroll
    for (int d = 0; d < SA_DIM; d++) {
      float s1 = 0.f, s2 = 0.f;
#pragma unroll
      for (int e = 0; e < SA_DIM; e++) { s1 += Ai[d * SA_DIM + e] * nu[e]; s2 += Ai[d * SA_DIM + e] * xi[e]; }
      sv[d] = s1;
      ad[d] = s2;
    }
    float mq = 0.f;
#pragma unroll
    for (int d = 0; d < SA_DIM; d++) mq += nu[d] * sv[d];
    float mexp = mdcw[g] * __expf(-0.5f * mq);
    float cm = bg * mexp;
    float contrib[SA_DIM];
#pragma unroll
    for (int d = 0; d < SA_DIM; d++) {
      float ccm = sc[d] * aims[d];
#pragma unroll
      for (int jj = 0; jj < SA_DIM; jj++) ccm += cv[d * SA_DIM + jj] * ad[jj];
      contrib[d] = mexp * ccm * bg;
    }
    red[i] = cm;
    __syncthreads();
    for (int st = 128; st > 0; st >>= 1) {
      if (i < st) red[i] += red[i + st];
      __syncthreads();
    }
    if (i == 0) meanw[g] = red[0];
    for (int d = 0; d < SA_DIM; d++) {
      __syncthreads();
      red[i] = contrib[d];
      __syncthreads();
      for (int st = 128; st > 0; st >>= 1) {
        if (i < st) red[i] += red[i + st];
        __syncthreads();
      }
      if (i == 0) crossw[d * S_DIM + g] = red[0];
    }
  }
}

// ---------------- K8: final assembly ----------------
__global__ __launch_bounds__(64) void k_final(const float* __restrict__ covp,
                                              const float* __restrict__ trp,
                                              const float* __restrict__ meanw,
                                              const float* __restrict__ crossw,
                                              const float* __restrict__ cov,
                                              const float* __restrict__ eqc,
                                              const float* __restrict__ mf,
                                              float* __restrict__ out) {
  int p = threadIdx.x;
  if (p >= 64) return;
  int a = p >> 3, b = p & 7;
  float covq = 0.f;
#pragma unroll
  for (int e = 0; e < 8; e++) covq += covp[p * 8 + e];
  float ma = meanw[a], mb = meanw[b];
  float val = covq - ma * mb + cov[a * SA_DIM + b];
  if (a == b) {
    float tr = 0.f;
#pragma unroll
    for (int e = 0; e < 8; e++) tr += trp[a * 8 + e];
    val += eqc[a] - tr;
  }
  val += (crossw[a * S_DIM + b] - mf[a] * mb) + (crossw[b * S_DIM + a] - mf[b] * ma);
  out[S_DIM + p] = val;
  if (p < S_DIM) out[p] = meanw[p] + mf[p];
}

extern "C" void kernel_launch(void* const* d_in, const int* in_sizes, int n_in,
                              void* d_out, int out_size, void* d_ws, size_t ws_size,
                              hipStream_t stream) {
  const float* mf     = (const float*)d_in[0];  // [10]
  const float* cov    = (const float*)d_in[1];  // [10,10]
  const float* x      = (const float*)d_in[2];  // [256,10]
  const float* y      = (const float*)d_in[3];  // [256,8]
  const float* eqc    = (const float*)d_in[4];  // [8]
  const float* scales = (const float*)d_in[5];  // [8,10]
  const float* noise  = (const float*)d_in[6];  // [8]
  float* ws = (float*)d_ws;

  float* Kw    = ws + OFF_K;     // K, then LT in place
  float* Linv  = ws + OFF_LINV;
  float* Kinv  = ws + OFF_KINV;
  float* rd    = ws + OFF_RD;
  float* u     = ws + OFF_U;
  float* lkw   = ws + OFF_LK;
  float* Mw    = ws + OFF_M;
  float* cvec  = ws + OFF_C;
  float* Ainvw = ws + OFF_AINV;
  float* aimw  = ws + OFF_AIM;
  float* mdcw  = ws + OFF_MDC;
  float* betaw = ws + OFF_BETA;
  float* meanw = ws + OFF_MEAN;
  float* crossw= ws + OFF_CROSS;
  float* covp  = ws + OFF_COVP;
  float* trp   = ws + OFF_TRP;

  k_front9<<<9, 256, 0, stream>>>(x, mf, cov, eqc, scales, u, lkw, Mw, cvec,
                                  Ainvw, aimw, mdcw);
  k_cholK<<<8, 1024, 0, stream>>>(x, eqc, scales, noise, Kw, rd);
  k_linv2<<<32, 256, 0, stream>>>(Kw, rd, Linv);
  k_syrk2<<<80, 256, 0, stream>>>(Linv, Kinv);
  k_beta<<<8, 256, 0, stream>>>(Kinv, y, betaw);
  k_back<<<520, 256, 0, stream>>>(u, lkw, Mw, cvec, Kinv, betaw, x, mf, cov, scales,
                                  Ainvw, aimw, mdcw, covp, trp, meanw, crossw);
  k_final<<<1, 64, 0, stream>>>(covp, trp, meanw, crossw, cov, eqc, mf, (float*)d_out);
}

// Round 17
// 268.359 us; speedup vs baseline: 1.0412x; 1.0412x over previous
//
#include <hip/hip_runtime.h>
#include <math.h>

#define S_DIM 8
#define SA_DIM 10
#define NN 256

// ---------------- workspace layout (float offsets) ----------------
constexpr size_t OFF_K     = 0;                          // 8*256*256  (K, then LT in-place: LT[k][i] = L[i][k])
constexpr size_t OFF_LINV  = OFF_K    + 8ull*NN*NN;      // 8*256*256
constexpr size_t OFF_KINV  = OFF_LINV + 8ull*NN*NN;      // 8*256*256
constexpr size_t OFF_RD    = OFF_KINV + 8ull*NN*NN;      // 8*256 reciprocal diag of L
constexpr size_t OFF_U     = OFF_RD   + 8*NN;            // 8*256*10  u = (x-mean)*inv_scales
constexpr size_t OFF_LK    = OFF_U    + 8*NN*SA_DIM;     // 8*256     log k(mean, x_n)
constexpr size_t OFF_M     = OFF_LK   + 8*NN;            // 64*100    M_ab
constexpr size_t OFF_C     = OFF_M    + 64*100;          // 64        -0.5*logdet R
constexpr size_t OFF_AINV  = OFF_C    + 64;              // 8*100
constexpr size_t OFF_AIM   = OFF_AINV + 800;             // 8*10      Ainv @ mean
constexpr size_t OFF_MDC   = OFF_AIM  + 80;              // 8         mean det coeff
constexpr size_t OFF_BETA  = OFF_MDC  + 8;               // 8*256     beta
constexpr size_t OFF_MEAN  = OFF_BETA + 8*NN;            // 8
constexpr size_t OFF_CROSS = OFF_MEAN + 8;               // 80  cross_cov[d][g]
constexpr size_t OFF_COVP  = OFF_CROSS+ 80;              // 256 partials
constexpr size_t OFF_TRP   = OFF_COVP + 256;             // 32  trace partials

// ---------------- Gauss-Jordan inverse, 10x10, no pivoting (matrices are I+PSD-like) ----
__device__ void gj_invert10(float A[SA_DIM][SA_DIM], float B[SA_DIM][SA_DIM], float* logdet) {
#pragma unroll
  for (int i = 0; i < SA_DIM; i++)
#pragma unroll
    for (int j = 0; j < SA_DIM; j++) B[i][j] = (i == j) ? 1.f : 0.f;
  float ld = 0.f;
#pragma unroll
  for (int k = 0; k < SA_DIM; k++) {
    float pv = A[k][k];
    ld += logf(pv);
    float ip = 1.f / pv;
#pragma unroll
    for (int j = 0; j < SA_DIM; j++) { A[k][j] *= ip; B[k][j] *= ip; }
#pragma unroll
    for (int r = 0; r < SA_DIM; r++) {
      if (r == k) continue;
      float f = A[r][k];
#pragma unroll
      for (int j = 0; j < SA_DIM; j++) { A[r][j] -= f * A[k][j]; B[r][j] -= f * B[k][j]; }
    }
  }
  *logdet = ld;
}

// ---------------- K-front: build K  |  prep u/lk  |  small 10x10 linear algebra --------
__global__ __launch_bounds__(256) void k_front(const float* __restrict__ x,
                                               const float* __restrict__ mf,
                                               const float* __restrict__ cov,
                                               const float* __restrict__ eqc,
                                               const float* __restrict__ scales,
                                               const float* __restrict__ noise,
                                               float* __restrict__ Kw,
                                               float* __restrict__ u,
                                               float* __restrict__ lkw,
                                               float* __restrict__ Mw, float* __restrict__ cvec,
                                               float* __restrict__ Ainvw, float* __restrict__ aimw,
                                               float* __restrict__ mdcw) {
  int blk = blockIdx.x;
  if (blk < 2048) {
    int g = blk >> 8;
    int n = blk & 255;
    int m = threadIdx.x;
    __shared__ float xs[NN * SA_DIM];
    __shared__ float isc[SA_DIM];
    for (int i = threadIdx.x; i < NN * SA_DIM; i += 256) xs[i] = x[i];
    if (threadIdx.x < SA_DIM) isc[threadIdx.x] = 1.0f / scales[g * SA_DIM + threadIdx.x];
    __syncthreads();
    float quad = 0.f;
#pragma unroll
    for (int d = 0; d < SA_DIM; d++) {
      float df = xs[n * SA_DIM + d] - xs[m * SA_DIM + d];
      quad += df * df * isc[d];
    }
    float v = eqc[g] * __expf(-0.5f * quad);
    if (m == n) v += noise[g];
    Kw[(size_t)g * NN * NN + (size_t)n * NN + m] = v;
  } else if (blk < 2056) {
    int g = blk - 2048;
    int n = threadIdx.x;
    float quad = 0.f;
#pragma unroll
    for (int d = 0; d < SA_DIM; d++) {
      float isc = 1.0f / scales[g * SA_DIM + d];
      float nu = x[n * SA_DIM + d] - mf[d];
      u[((size_t)g * NN + n) * SA_DIM + d] = nu * isc;
      quad += nu * nu * isc;
    }
    lkw[g * NN + n] = logf(eqc[g]) - 0.5f * quad;
  } else {
    int p = threadIdx.x;
    if (p >= 64) return;
    int a = p >> 3, b = p & 7;
    float A[SA_DIM][SA_DIM], B[SA_DIM][SA_DIM];
    for (int i = 0; i < SA_DIM; i++)
      for (int j = 0; j < SA_DIM; j++)
        A[i][j] = cov[i * SA_DIM + j] * (1.f / scales[a * SA_DIM + j] + 1.f / scales[b * SA_DIM + j]) +
                  ((i == j) ? 1.f : 0.f);
    float ld;
    gj_invert10(A, B, &ld);
    cvec[p] = -0.5f * ld;
    for (int i = 0; i < SA_DIM; i++)
      for (int j = 0; j < SA_DIM; j++) {
        float v = 0.f;
        for (int k = 0; k < SA_DIM; k++) v += B[i][k] * cov[k * SA_DIM + j];
        Mw[p * 100 + i * SA_DIM + j] = v;
      }
    if (b == 0) {
      int g = a;
      for (int i = 0; i < SA_DIM; i++)
        for (int j = 0; j < SA_DIM; j++)
          A[i][j] = cov[i * SA_DIM + j] + ((i == j) ? scales[g * SA_DIM + j] : 0.f);
      float ld2;
      gj_invert10(A, B, &ld2);
      for (int i = 0; i < SA_DIM; i++)
        for (int j = 0; j < SA_DIM; j++) Ainvw[g * 100 + i * SA_DIM + j] = B[i][j];
      for (int i = 0; i < SA_DIM; i++) {
        float v = 0.f;
        for (int j = 0; j < SA_DIM; j++) v += B[i][j] * mf[j];
        aimw[g * SA_DIM + i] = v;
      }
      for (int i = 0; i < SA_DIM; i++)
        for (int j = 0; j < SA_DIM; j++)
          A[i][j] = cov[i * SA_DIM + j] * (1.f / scales[g * SA_DIM + j]) + ((i == j) ? 1.f : 0.f);
      float ld3;
      gj_invert10(A, B, &ld3);
      mdcw[g] = eqc[g] * __expf(-0.5f * ld3);
    }
  }
}

__device__ __forceinline__ void tile_idx(int tau, int ntile, int nt4, int c0,
                                         int& ib, int& jb, int& iq, int& jq) {
  int rt = ntile - 1 - tau;
  int q = (int)((sqrtf((float)(8 * rt + 1)) - 1.0f) * 0.5f);
  while ((q + 1) * (q + 2) / 2 <= rt) q++;
  while (q * (q + 1) / 2 > rt) q--;
  jq = nt4 - 1 - q;
  int rem = rt - q * (q + 1) / 2;
  iq = nt4 - 1 - rem;
  jb = c0 + 16 + 4 * jq;
  ib = c0 + 16 + 4 * iq;
}

// ---- factor one 16-col panel (proven chol8 body) ----
__device__ __forceinline__ void chol_factor_panel(float* __restrict__ Ag,
                                                  float* __restrict__ rdg,
                                                  int c0, int nb, int t, int lane,
                                                  bool fromGlobal,
                                                  const float (*SRC)[248],
                                                  float (*Pdst)[248]) {
  int rr = lane & 15;
  float a[16];
  float myrs = 0.f;
  if (fromGlobal) {
#pragma unroll
    for (int j = 0; j < 16; j++)
      a[j] = (j <= rr) ? Ag[(size_t)(c0 + j) * NN + (c0 + rr)]
                       : Ag[(size_t)(c0 + rr) * NN + (c0 + j)];
  } else {
#pragma unroll
    for (int j = 0; j < 16; j++)
      a[j] = (j <= rr) ? SRC[j][rr] : SRC[rr][j];
  }
#pragma unroll
  for (int k = 0; k < 16; k++) {
    float d = __shfl(a[k], k);
    float rs_ = rsqrtf(d);
    if (rr == k) myrs = rs_;
    float m = a[k] * rs_;
#pragma unroll
    for (int j = 0; j < 16; j++) {
      if (j > k) {
        float Lkj = __shfl(a[j], k) * rs_;
        a[j] = fmaf(-m, Lkj, a[j]);
      }
    }
    a[k] = m;
  }
  if (t < 16) {
    rdg[c0 + rr] = myrs;
#pragma unroll
    for (int j = 0; j < 16; j++)
      if (j <= rr) Ag[(size_t)(c0 + j) * NN + (c0 + rr)] = a[j];
  }
  if (t < nb) {
    int i = c0 + 16 + t;
    float xs[16];
#pragma unroll
    for (int c = 0; c < 16; c++) {
      float x = fromGlobal ? Ag[(size_t)(c0 + c) * NN + i] : SRC[c][16 + t];
#pragma unroll
      for (int cp = 0; cp < 16; cp++) {
        if (cp < c) {
          float Lccp = __shfl(a[cp], c);
          x = fmaf(-Lccp, xs[cp], x);
        }
      }
      xs[c] = x * __shfl(myrs, c);
    }
#pragma unroll
    for (int c = 0; c < 16; c++) {
      Ag[(size_t)(c0 + c) * NN + i] = xs[c];
      Pdst[c][t] = xs[c];
    }
  }
}

// ---------------- K1: lookahead right-looking Cholesky (chol8, empirical best 104us) ----
__global__ __launch_bounds__(1024, 4) void k_chol8(float* __restrict__ Aw,
                                                   float* __restrict__ rd) {
  int g = blockIdx.x;
  float* Ag = Aw + (size_t)g * NN * NN;
  float* rdg = rd + g * NN;
  int t = threadIdx.x;
  int lane = t & 63;
  int w = t >> 6;
  __shared__ __align__(16) float P[2][16][248];
  __shared__ __align__(16) float NP[16][248];

  if (w < 4)
    chol_factor_panel(Ag, rdg, 0, 240, t, lane, true, nullptr, P[0]);
  __syncthreads();

  for (int p = 0; p < 15; p++) {
    int c0 = 16 * p;
    int nb = NN - c0 - 16;   // >= 16
    int nt4 = nb >> 2;       // >= 4
    const float (*Pc)[248] = P[p & 1];
    // ---------------- C(p): critical tiles (jq < 4) -> NP, LDS only ----------------
    int ncrit = 4 * nt4 - 6;
    if (t < ncrit) {
      int jq, iq;
      if (t < nt4) { jq = 0; iq = t; }
      else if (t < 2 * nt4 - 1) { jq = 1; iq = t - nt4 + 1; }
      else if (t < 3 * nt4 - 3) { jq = 2; iq = t - (2 * nt4 - 1) + 2; }
      else { jq = 3; iq = t - (3 * nt4 - 3) + 3; }
      int jb = c0 + 16 + 4 * jq, ib = c0 + 16 + 4 * iq;
      float4 cv0 = *(const float4*)(Ag + (size_t)(jb + 0) * NN + ib);
      float4 cv1 = *(const float4*)(Ag + (size_t)(jb + 1) * NN + ib);
      float4 cv2 = *(const float4*)(Ag + (size_t)(jb + 2) * NN + ib);
      float4 cv3 = *(const float4*)(Ag + (size_t)(jb + 3) * NN + ib);
      float4 a0 = make_float4(0.f, 0.f, 0.f, 0.f), a1 = a0, a2 = a0, a3 = a0;
#pragma unroll
      for (int k = 0; k < 16; k++) {
        float4 pi = *(const float4*)(&Pc[k][4 * iq]);
        float4 pj = *(const float4*)(&Pc[k][4 * jq]);
        a0.x = fmaf(pj.x, pi.x, a0.x); a0.y = fmaf(pj.x, pi.y, a0.y);
        a0.z = fmaf(pj.x, pi.z, a0.z); a0.w = fmaf(pj.x, pi.w, a0.w);
        a1.x = fmaf(pj.y, pi.x, a1.x); a1.y = fmaf(pj.y, pi.y, a1.y);
        a1.z = fmaf(pj.y, pi.z, a1.z); a1.w = fmaf(pj.y, pi.w, a1.w);
        a2.x = fmaf(pj.z, pi.x, a2.x); a2.y = fmaf(pj.z, pi.y, a2.y);
        a2.z = fmaf(pj.z, pi.z, a2.z); a2.w = fmaf(pj.z, pi.w, a2.w);
        a3.x = fmaf(pj.w, pi.x, a3.x); a3.y = fmaf(pj.w, pi.y, a3.y);
        a3.z = fmaf(pj.w, pi.z, a3.z); a3.w = fmaf(pj.w, pi.w, a3.w);
      }
      cv0.x -= a0.x; cv0.y -= a0.y; cv0.z -= a0.z; cv0.w -= a0.w;
      cv1.x -= a1.x; cv1.y -= a1.y; cv1.z -= a1.z; cv1.w -= a1.w;
      cv2.x -= a2.x; cv2.y -= a2.y; cv2.z -= a2.z; cv2.w -= a2.w;
      cv3.x -= a3.x; cv3.y -= a3.y; cv3.z -= a3.z; cv3.w -= a3.w;
      *(float4*)(&NP[4 * jq + 0][4 * iq]) = cv0;
      *(float4*)(&NP[4 * jq + 1][4 * iq]) = cv1;
      *(float4*)(&NP[4 * jq + 2][4 * iq]) = cv2;
      *(float4*)(&NP[4 * jq + 3][4 * iq]) = cv3;
    }
    __syncthreads();
    if (w < 4) {
      // ---------------- F(p+1) from NP ----------------
      chol_factor_panel(Ag, rdg, c0 + 16, nb - 16, t, lane, false, NP, P[(p + 1) & 1]);
    } else {
      // ---------------- B(p): bulk tiles (jq >= 4), read/write global ----------------
      int nt4b = nt4 - 4;
      int ntileB = nt4b * (nt4b + 1) / 2;
      for (int tau = t - 256; tau < ntileB; tau += 768) {
        int ib, jb, iq, jq;
        tile_idx(tau, ntileB, nt4b, c0 + 16, ib, jb, iq, jq);
        float4 cv0 = *(const float4*)(Ag + (size_t)(jb + 0) * NN + ib);
        float4 cv1 = *(const float4*)(Ag + (size_t)(jb + 1) * NN + ib);
        float4 cv2 = *(const float4*)(Ag + (size_t)(jb + 2) * NN + ib);
        float4 cv3 = *(const float4*)(Ag + (size_t)(jb + 3) * NN + ib);
        float4 a0 = make_float4(0.f, 0.f, 0.f, 0.f), a1 = a0, a2 = a0, a3 = a0;
#pragma unroll
        for (int k = 0; k < 16; k++) {
          float4 pi = *(const float4*)(&Pc[k][16 + 4 * iq]);
          float4 pj = *(const float4*)(&Pc[k][16 + 4 * jq]);
          a0.x = fmaf(pj.x, pi.x, a0.x); a0.y = fmaf(pj.x, pi.y, a0.y);
          a0.z = fmaf(pj.x, pi.z, a0.z); a0.w = fmaf(pj.x, pi.w, a0.w);
          a1.x = fmaf(pj.y, pi.x, a1.x); a1.y = fmaf(pj.y, pi.y, a1.y);
          a1.z = fmaf(pj.y, pi.z, a1.z); a1.w = fmaf(pj.y, pi.w, a1.w);
          a2.x = fmaf(pj.z, pi.x, a2.x); a2.y = fmaf(pj.z, pi.y, a2.y);
          a2.z = fmaf(pj.z, pi.z, a2.z); a2.w = fmaf(pj.z, pi.w, a2.w);
          a3.x = fmaf(pj.w, pi.x, a3.x); a3.y = fmaf(pj.w, pi.y, a3.y);
          a3.z = fmaf(pj.w, pi.z, a3.z); a3.w = fmaf(pj.w, pi.w, a3.w);
        }
        cv0.x -= a0.x; cv0.y -= a0.y; cv0.z -= a0.z; cv0.w -= a0.w;
        cv1.x -= a1.x; cv1.y -= a1.y; cv1.z -= a1.z; cv1.w -= a1.w;
        cv2.x -= a2.x; cv2.y -= a2.y; cv2.z -= a2.z; cv2.w -= a2.w;
        cv3.x -= a3.x; cv3.y -= a3.y; cv3.z -= a3.z; cv3.w -= a3.w;
        *(float4*)(Ag + (size_t)(jb + 0) * NN + ib) = cv0;
        *(float4*)(Ag + (size_t)(jb + 1) * NN + ib) = cv1;
        *(float4*)(Ag + (size_t)(jb + 2) * NN + ib) = cv2;
        *(float4*)(Ag + (size_t)(jb + 3) * NN + ib) = cv3;
      }
    }
    __syncthreads();
  }
}

// ---------------- K2: BLOCKED triangular inverse -------------------------------------
__global__ __launch_bounds__(256) void k_linv2(const float* __restrict__ LT,
                                               const float* __restrict__ rd,
                                               float* __restrict__ Linv) {
  int g = blockIdx.x >> 2;
  int q = blockIdx.x & 3;
  int w = threadIdx.x >> 6;
  int lane = threadIdx.x & 63;
  int j = 4 * q + w;
  const float* Ag = LT + (size_t)g * NN * NN;
  const float* rdg = rd + g * NN;
  float* Og = Linv + (size_t)g * NN * NN;
  __shared__ __align__(16) float Xl[4][16][16][16];
  __shared__ __align__(16) float Dv[16][16][16];
  int r = lane & 15, cq = lane >> 4;

  for (int s = 0; s < 4; s++) {
    int i = w + 4 * s;
    for (int e = lane; e < 256; e += 64) {
      int k = e >> 4, rr = e & 15;
      Xl[w][s][k][rr] = Ag[(size_t)(16 * i + k) * NN + 16 * i + rr];
    }
    asm volatile("s_waitcnt lgkmcnt(0)" ::: "memory");
    __builtin_amdgcn_sched_barrier(0);
    int c = lane & 15;
    float xv[16];
#pragma unroll
    for (int rr = 0; rr < 16; rr++) {
      float tmp = (rr == c) ? 1.f : 0.f;
#pragma unroll
      for (int m = 0; m < 16; m++) {
        if (m < rr) tmp = fmaf(-Xl[w][s][m][rr], xv[m], tmp);
      }
      xv[rr] = tmp * rdg[16 * i + rr];
    }
    if (lane < 16) {
#pragma unroll
      for (int rr = 0; rr < 16; rr++) Dv[i][rr][lane] = xv[rr];
    }
  }
  __syncthreads();

  {
    float4 dj = *(const float4*)&Dv[j][r][4 * cq];
    *(float4*)&Xl[w][j][r][4 * cq] = dj;
    *(float4*)(Og + (size_t)(16 * j + r) * NN + 16 * j + 4 * cq) = dj;
    float4 z = make_float4(0.f, 0.f, 0.f, 0.f);
    for (int i2 = 0; i2 < j; i2++)
      *(float4*)(Og + (size_t)(16 * i2 + r) * NN + 16 * j + 4 * cq) = z;
  }
  asm volatile("s_waitcnt lgkmcnt(0)" ::: "memory");
  __builtin_amdgcn_sched_barrier(0);

  for (int i = j + 1; i < 16; i++) {
    float4 acc = make_float4(0.f, 0.f, 0.f, 0.f);
    for (int k = j; k < i; k++) {
      const float* Lbase = Ag + (size_t)(16 * k) * NN + 16 * i + r;
      const float* Xk = &Xl[w][k][0][4 * cq];
#pragma unroll
      for (int m = 0; m < 16; m++) {
        float lv = Lbase[(size_t)m * NN];
        float4 xvv = *(const float4*)(Xk + 16 * m);
        acc.x = fmaf(lv, xvv.x, acc.x);
        acc.y = fmaf(lv, xvv.y, acc.y);
        acc.z = fmaf(lv, xvv.z, acc.z);
        acc.w = fmaf(lv, xvv.w, acc.w);
      }
    }
    float4 o = make_float4(0.f, 0.f, 0.f, 0.f);
#pragma unroll
    for (int m = 0; m < 16; m++) {
      float d = Dv[i][r][m];
      float sx = __shfl(acc.x, m + 16 * cq);
      float sy = __shfl(acc.y, m + 16 * cq);
      float sz = __shfl(acc.z, m + 16 * cq);
      float sw = __shfl(acc.w, m + 16 * cq);
      o.x = fmaf(-d, sx, o.x);
      o.y = fmaf(-d, sy, o.y);
      o.z = fmaf(-d, sz, o.z);
      o.w = fmaf(-d, sw, o.w);
    }
    *(float4*)&Xl[w][i][r][4 * cq] = o;
    *(float4*)(Og + (size_t)(16 * i + r) * NN + 16 * j + 4 * cq) = o;
    asm volatile("s_waitcnt lgkmcnt(0)" ::: "memory");
    __builtin_amdgcn_sched_barrier(0);
  }
}

// ---------------- K3: Kinv = Linv^T Linv (tiled SYRK-as-GEMM) ----------------
__global__ __launch_bounds__(256) void k_syrk(const float* __restrict__ Linv,
                                              float* __restrict__ Kinv) {
  int g = blockIdx.x >> 4;
  int tile = blockIdx.x & 15;
  int i0 = (tile >> 2) * 64, j0 = (tile & 3) * 64;
  const float* A = Linv + (size_t)g * NN * NN;
  float* O = Kinv + (size_t)g * NN * NN;
  __shared__ float sa[32][64], sb[32][64];
  int tx = threadIdx.x & 15, ty = threadIdx.x >> 4;
  float acc[4][4] = {{0.f}};
  for (int k0 = 0; k0 < NN; k0 += 32) {
    for (int e = threadIdx.x; e < 2048; e += 256) {
      int kk = e >> 6, cc = e & 63;
      sa[kk][cc] = A[(size_t)(k0 + kk) * NN + i0 + cc];
      sb[kk][cc] = A[(size_t)(k0 + kk) * NN + j0 + cc];
    }
    __syncthreads();
#pragma unroll 8
    for (int kk = 0; kk < 32; kk++) {
      float av[4], bv[4];
#pragma unroll
      for (int q = 0; q < 4; q++) { av[q] = sa[kk][ty * 4 + q]; bv[q] = sb[kk][tx * 4 + q]; }
#pragma unroll
      for (int q = 0; q < 4; q++)
#pragma unroll
        for (int r = 0; r < 4; r++) acc[q][r] += av[q] * bv[r];
    }
    __syncthreads();
  }
#pragma unroll
  for (int q = 0; q < 4; q++)
#pragma unroll
    for (int r = 0; r < 4; r++)
      O[(size_t)(i0 + ty * 4 + q) * NN + j0 + tx * 4 + r] = acc[q][r];
}

// ---------------- K4: beta = Kinv @ y (once, 8 blocks) ----------------
__global__ __launch_bounds__(256) void k_beta(const float* __restrict__ Kinv,
                                              const float* __restrict__ y,
                                              float* __restrict__ betaw) {
  int g = blockIdx.x, n = threadIdx.x;
  __shared__ __align__(16) float ys[NN];
  ys[n] = y[n * S_DIM + g];
  __syncthreads();
  const float4* Kg = (const float4*)(Kinv + (size_t)g * NN * NN + (size_t)n * NN);
  float acc = 0.f;
  for (int m4 = 0; m4 < 64; m4++) {
    float4 kv = Kg[m4];
    float4 yv = ((const float4*)ys)[m4];
    acc += kv.x * yv.x + kv.y * yv.y + kv.z * yv.z + kv.w * yv.w;
  }
  betaw[g * NN + n] = acc;
}

// ---------------- K-back: fused Q reduction (blocks 0..255) + mean/cross (256..263) ------
__global__ __launch_bounds__(256) void k_back(const float* __restrict__ u,
                                              const float* __restrict__ lkw,
                                              const float* __restrict__ Mw,
                                              const float* __restrict__ cvec,
                                              const float* __restrict__ Kinv,
                                              const float* __restrict__ betaw,
                                              const float* __restrict__ x,
                                              const float* __restrict__ mf,
                                              const float* __restrict__ cov,
                                              const float* __restrict__ scales,
                                              const float* __restrict__ Ainvw,
                                              const float* __restrict__ aimw,
                                              const float* __restrict__ mdcw,
                                              float* __restrict__ covp, float* __restrict__ trp,
                                              float* __restrict__ meanw, float* __restrict__ crossw) {
  int blk = blockIdx.x;
  int t = threadIdx.x;
  if (blk < 256) {
    int p = blk >> 2;
    int quarter = blk & 3;
    int a = p >> 3, b = p & 7;
    __shared__ __align__(16) float ub[NN * 12];
    __shared__ float Ms[100];
    __shared__ float sbv[NN];
    __shared__ float eb[NN];
    __shared__ float red[256];
    {
      const float* ur = u + (size_t)b * NN * SA_DIM + (size_t)t * SA_DIM;
      float* ud = &ub[t * 12];
#pragma unroll
      for (int d = 0; d < SA_DIM; d++) ud[d] = ur[d];
    }
    if (t < 100) Ms[t] = Mw[p * 100 + t];
    eb[t] = betaw[b * NN + t];
    __syncthreads();
    {
      const float* um = &ub[t * 12];
      float qd = 0.f;
#pragma unroll
      for (int d = 0; d < SA_DIM; d++) {
        float v = 0.f;
#pragma unroll
        for (int e = 0; e < SA_DIM; e++) v += Ms[d * SA_DIM + e] * um[e];
        qd += v * um[d];
      }
      sbv[t] = lkw[b * NN + t] + 0.5f * qd;
    }
    __syncthreads();
    int n = quarter * 64 + (t >> 2);
    int c = t & 3;
    float ua[SA_DIM];
#pragma unroll
    for (int d = 0; d < SA_DIM; d++) ua[d] = u[((size_t)a * NN + n) * SA_DIM + d];
    float va[SA_DIM];
#pragma unroll
    for (int d = 0; d < SA_DIM; d++) {
      float v = 0.f;
#pragma unroll
      for (int e = 0; e < SA_DIM; e++) v += Ms[d * SA_DIM + e] * ua[e];
      va[d] = v;
    }
    float qa = 0.f;
#pragma unroll
    for (int d = 0; d < SA_DIM; d++) qa += va[d] * ua[d];
    float pa = lkw[a * NN + n] + 0.5f * qa + cvec[p];
    float wa = betaw[a * NN + n];
    const float* Krow = Kinv + (size_t)a * NN * NN + (size_t)n * NN;
    float covacc = 0.f, tracc = 0.f;
    bool dg = (a == b);
    for (int ii = 0; ii < 64; ii++) {
      int mm = c + 4 * ii;
      const float* ur = &ub[mm * 12];
      float4 f0 = *(const float4*)ur;
      float4 f1 = *(const float4*)(ur + 4);
      float4 f2 = *(const float4*)(ur + 8);
      float s = pa + sbv[mm];
      s += va[0] * f0.x + va[1] * f0.y + va[2] * f0.z + va[3] * f0.w;
      s += va[4] * f1.x + va[5] * f1.y + va[6] * f1.z + va[7] * f1.w;
      s += va[8] * f2.x + va[9] * f2.y;
      float e = __expf(s);
      covacc += eb[mm] * e;
      if (dg) tracc += Krow[mm] * e;
    }
    covacc *= wa;
    red[t] = covacc;
    __syncthreads();
    for (int st = 128; st > 0; st >>= 1) {
      if (t < st) red[t] += red[t + st];
      __syncthreads();
    }
    if (t == 0) covp[blk] = red[0];
    if (dg) {
      red[t] = tracc;
      __syncthreads();
      for (int st = 128; st > 0; st >>= 1) {
        if (t < st) red[t] += red[t + st];
        __syncthreads();
      }
      if (t == 0) trp[a * 4 + quarter] = red[0];
    }
  } else {
    int g = blk - 256;
    int i = t;
    __shared__ float Ai[100], cv[100], aims[SA_DIM], sc[SA_DIM], mfs[SA_DIM];
    __shared__ float red[256];
    if (i < 100) { Ai[i] = Ainvw[g * 100 + i]; cv[i] = cov[i]; }
    if (i < SA_DIM) { aims[i] = aimw[g * SA_DIM + i]; sc[i] = scales[g * SA_DIM + i]; mfs[i] = mf[i]; }
    __syncthreads();
    float bg = betaw[g * NN + i];
    float xi[SA_DIM], nu[SA_DIM];
#pragma unroll
    for (int d = 0; d < SA_DIM; d++) { xi[d] = x[i * SA_DIM + d]; nu[d] = xi[d] - mfs[d]; }
    float sv[SA_DIM], ad[SA_DIM];
#pragma unroll
    for (int d = 0; d < SA_DIM; d++) {
      float s1 = 0.f, s2 = 0.f;
#pragma unroll
      for (int e = 0; e < SA_DIM; e++) { s1 += Ai[d * SA_DIM + e] * nu[e]; s2 += Ai[d * SA_DIM + e] * xi[e]; }
      sv[d] = s1;
      ad[d] = s2;
    }
    float mq = 0.f;
#pragma unroll
    for (int d = 0; d < SA_DIM; d++) mq += nu[d] * sv[d];
    float mexp = mdcw[g] * __expf(-0.5f * mq);
    float cm = bg * mexp;
    float contrib[SA_DIM];
#pragma unroll
    for (int d = 0; d < SA_DIM; d++) {
      float ccm = sc[d] * aims[d];
#pragma unroll
      for (int jj = 0; jj < SA_DIM; jj++) ccm += cv[d * SA_DIM + jj] * ad[jj];
      contrib[d] = mexp * ccm * bg;
    }
    red[i] = cm;
    __syncthreads();
    for (int st = 128; st > 0; st >>= 1) {
      if (i < st) red[i] += red[i + st];
      __syncthreads();
    }
    if (i == 0) meanw[g] = red[0];
    for (int d = 0; d < SA_DIM; d++) {
      __syncthreads();
      red[i] = contrib[d];
      __syncthreads();
      for (int st = 128; st > 0; st >>= 1) {
        if (i < st) red[i] += red[i + st];
        __syncthreads();
      }
      if (i == 0) crossw[d * S_DIM + g] = red[0];
    }
  }
}

// ---------------- K8: final assembly ----------------
__global__ __launch_bounds__(64) void k_final(const float* __restrict__ covp,
                                              const float* __restrict__ trp,
                                              const float* __restrict__ meanw,
                                              const float* __restrict__ crossw,
                                              const float* __restrict__ cov,
                                              const float* __restrict__ eqc,
                                              const float* __restrict__ mf,
                                              float* __restrict__ out) {
  int p = threadIdx.x;
  if (p >= 64) return;
  int a = p >> 3, b = p & 7;
  float covq = covp[p * 4] + covp[p * 4 + 1] + covp[p * 4 + 2] + covp[p * 4 + 3];
  float ma = meanw[a], mb = meanw[b];
  float val = covq - ma * mb + cov[a * SA_DIM + b];
  if (a == b) {
    float tr = trp[a * 4] + trp[a * 4 + 1] + trp[a * 4 + 2] + trp[a * 4 + 3];
    val += eqc[a] - tr;
  }
  val += (crossw[a * S_DIM + b] - mf[a] * mb) + (crossw[b * S_DIM + a] - mf[b] * ma);
  out[S_DIM + p] = val;
  if (p < S_DIM) out[p] = meanw[p] + mf[p];
}

extern "C" void kernel_launch(void* const* d_in, const int* in_sizes, int n_in,
                              void* d_out, int out_size, void* d_ws, size_t ws_size,
                              hipStream_t stream) {
  const float* mf     = (const float*)d_in[0];  // [10]
  const float* cov    = (const float*)d_in[1];  // [10,10]
  const float* x      = (const float*)d_in[2];  // [256,10]
  const float* y      = (const float*)d_in[3];  // [256,8]
  const float* eqc    = (const float*)d_in[4];  // [8]
  const float* scales = (const float*)d_in[5];  // [8,10]
  const float* noise  = (const float*)d_in[6];  // [8]
  float* ws = (float*)d_ws;

  float* Kw    = ws + OFF_K;     // K, then LT in place
  float* Linv  = ws + OFF_LINV;
  float* Kinv  = ws + OFF_KINV;
  float* rd    = ws + OFF_RD;
  float* u     = ws + OFF_U;
  float* lkw   = ws + OFF_LK;
  float* Mw    = ws + OFF_M;
  float* cvec  = ws + OFF_C;
  float* Ainvw = ws + OFF_AINV;
  float* aimw  = ws + OFF_AIM;
  float* mdcw  = ws + OFF_MDC;
  float* betaw = ws + OFF_BETA;
  float* meanw = ws + OFF_MEAN;
  float* crossw= ws + OFF_CROSS;
  float* covp  = ws + OFF_COVP;
  float* trp   = ws + OFF_TRP;

  k_front<<<2057, 256, 0, stream>>>(x, mf, cov, eqc, scales, noise, Kw, u, lkw, Mw, cvec,
                                    Ainvw, aimw, mdcw);
  k_chol8<<<8, 1024, 0, stream>>>(Kw, rd);
  k_linv2<<<32, 256, 0, stream>>>(Kw, rd, Linv);
  k_syrk<<<128, 256, 0, stream>>>(Linv, Kinv);
  k_beta<<<8, 256, 0, stream>>>(Kinv, y, betaw);
  k_back<<<264, 256, 0, stream>>>(u, lkw, Mw, cvec, Kinv, betaw, x, mf, cov, scales,
                                  Ainvw, aimw, mdcw, covp, trp, meanw, crossw);
  k_final<<<1, 64, 0, stream>>>(covp, trp, meanw, crossw, cov, eqc, mf, (float*)d_out);
}